// Round 17
// baseline (103.697 us; speedup 1.0000x reference)
//
#include <hip/hip_runtime.h>

#define H 12
#define DM 768
#define HD 64
#define SEQ 2048
#define BATCH 2
#define MROWS (BATCH*SEQ)   // 4096

typedef __attribute__((ext_vector_type(8))) short short8;    // 8 bf16 (4 VGPRs)
typedef __attribute__((ext_vector_type(4))) float f32x4;
typedef __attribute__((ext_vector_type(16))) float f32x16;
using u16 = unsigned short;
using u32 = unsigned int;

__device__ __forceinline__ float bf2f(u16 u) { return __uint_as_float(((u32)u) << 16); }
__device__ __forceinline__ u16 f2bf(float x) {
  u32 u = __float_as_uint(x);
  return (u16)((u + 0x7fffu + ((u >> 16) & 1u)) >> 16);   // RNE
}
// packed f32x2 -> bf16x2 (RNE), single instruction (T12 recipe: no builtin on gfx950)
__device__ __forceinline__ u32 cvt_pk_bf16(float lo, float hi) {
  u32 r;
  asm("v_cvt_pk_bf16_f32 %0, %1, %2" : "=v"(r) : "v"(lo), "v"(hi));
  return r;
}
// guaranteed single-instruction exp2 (trans pipe)
__device__ __forceinline__ float fexp2(float x) {
  float r;
  asm("v_exp_f32 %0, %1" : "=v"(r) : "v"(x));
  return r;
}
// async global->LDS, 16B per lane; LDS dest = wave-uniform base + lane*16 (m97/m104)
__device__ __forceinline__ void gl2lds16(const u16* __restrict__ g, u16* l) {
  __builtin_amdgcn_global_load_lds(
      (const __attribute__((address_space(1))) unsigned int*)g,
      (__attribute__((address_space(3))) unsigned int*)l,
      16, 0, 0);
}

#define C_SM 0.18033688011112042f   // (1/sqrt(64)) * log2(e), folded into K

// ------------- x f32 -> bf16 (one pass; GEMM staging then uses global_load_lds) -------------
__global__ __launch_bounds__(256) void convert_x(const float* __restrict__ xq, const float* __restrict__ xk,
                                                 const float* __restrict__ xv, u16* __restrict__ Xb)
{
  constexpr size_t N = (size_t)MROWS * DM;      // per-tensor elems (3,145,728)
  constexpr size_t TOT = 3 * N / 8;             // 8 elems per work-item
  for (size_t id = (size_t)blockIdx.x * 256 + threadIdx.x; id < TOT; id += (size_t)gridDim.x * 256) {
    const size_t e = id * 8;
    const int z = (int)(e / N);
    const size_t off = e - (size_t)z * N;
    const float* src = z == 0 ? xq : z == 1 ? xk : xv;
    float4 a0 = *reinterpret_cast<const float4*>(src + off);
    float4 a1 = *reinterpret_cast<const float4*>(src + off + 4);
    uint4 o;
    o.x = cvt_pk_bf16(a0.x, a0.y);
    o.y = cvt_pk_bf16(a0.z, a0.w);
    o.z = cvt_pk_bf16(a1.x, a1.y);
    o.w = cvt_pk_bf16(a1.z, a1.w);
    *reinterpret_cast<uint4*>(Xb + (size_t)z * N + off) = o;
  }
}

// ------------- weight transpose + f32->bf16: dst[e*768+d] = bf16(src[d*768+e]) -------------
__global__ __launch_bounds__(256) void transpose_w4(const float* __restrict__ w0, const float* __restrict__ w1,
                                                    const float* __restrict__ w2, const float* __restrict__ w3,
                                                    u16* __restrict__ dst0)
{
  __shared__ u16 Ts[64][72];                 // +8 pad, rows 144 B (16B-aligned)
  const float* src = blockIdx.z == 0 ? w0 : blockIdx.z == 1 ? w1 : blockIdx.z == 2 ? w2 : w3;
  u16* dst = dst0 + (size_t)blockIdx.z * DM * DM;
  const int t = threadIdx.x;
  const int r0 = blockIdx.y * 64, c0 = blockIdx.x * 64;
  const int row = t >> 2, cq = (t & 3) * 16;
  const float* sp = src + (size_t)(r0 + row) * DM + c0 + cq;
  #pragma unroll
  for (int g = 0; g < 4; ++g) {
    float4 a = *reinterpret_cast<const float4*>(sp + g * 4);
    Ts[row][cq + g * 4 + 0] = f2bf(a.x);
    Ts[row][cq + g * 4 + 1] = f2bf(a.y);
    Ts[row][cq + g * 4 + 2] = f2bf(a.z);
    Ts[row][cq + g * 4 + 3] = f2bf(a.w);
  }
  __syncthreads();
  union { uint4 v[2]; u16 e[16]; } pk;
  #pragma unroll
  for (int j = 0; j < 16; ++j) pk.e[j] = Ts[cq + j][row];
  uint4* dp = reinterpret_cast<uint4*>(dst + (size_t)(c0 + row) * DM + r0 + cq);
  dp[0] = pk.v[0];
  dp[1] = pk.v[1];
}

// ---------------- GEMM (all-bf16): C[m][n] = (A[m][:] . Bt[n][:] + bias[n]) * outScale -----
// 64x64 tile, BK=64, 4 waves (2x2, wave-tile 32x32). R14/T3+T4 pattern: triple-buffered
// global_load_lds staging (pre-swizzled source), prefetch 2 ahead, steady-state vmcnt(4)
// (never 0 in loop), 1 barrier/iter. XOR swizzle byte ^= (row&7)<<4 on read (T2/G4).
// mode 0: dst[B,H,S,HD] bf16 (Q,K)  mode 1: dst[B,H,HD,S] bf16 (V^T)  mode 2: dst[M,N] f32
__device__ __forceinline__ void gemm_bf16(const u16* __restrict__ A, const u16* __restrict__ Bt,
                                          const float* __restrict__ bias, void* __restrict__ dstv,
                                          int mode, int bx, int by, float outScale)
{
  __shared__ u16 As[3][64 * 64];   // 8KB x3
  __shared__ u16 Bs[3][64 * 64];   // 8KB x3  (48KB total -> 3 blocks/CU)
  const int t = threadIdx.x;
  const int lane = t & 63, w = t >> 6;
  const int l15 = lane & 15, l4 = lane >> 4;
  const int m0 = by * 64, n0 = bx * 64;
  const int wr = (w >> 1) * 32, wc = (w & 1) * 32;
  constexpr int NK = DM / 64;      // 12
  const int r8 = lane >> 3;
  const int pcol = ((lane & 7) ^ r8) * 8;   // pre-swizzled global col

  // stage K-tile kt2 into buffer buf: per wave 2 A-chunks + 2 B-chunks (4 gl2lds/lane)
  auto STAGE = [&](int kt2, int buf) {
    const int k0 = kt2 * 64;
    #pragma unroll
    for (int j = 0; j < 2; ++j) {
      const int ci = w * 2 + j;
      const int row = ci * 8 + r8;
      gl2lds16(A  + (size_t)(m0 + row) * DM + k0 + pcol, &As[buf][ci * 512]);
      gl2lds16(Bt + (size_t)(n0 + row) * DM + k0 + pcol, &Bs[buf][ci * 512]);
    }
  };

  STAGE(0, 0);
  STAGE(1, 1);

  f32x4 acc[2][2] = {};
  int cur = 0;   // buffer holding tile kt; rotates 0,1,2

  for (int kt = 0; kt < NK; ++kt) {
    // T4: wait only for tile kt's 4 loads; tile kt+1's stay in flight across the barrier
    asm volatile("s_waitcnt vmcnt(4)" ::: "memory");
    __builtin_amdgcn_s_barrier();

    // prefetch tile kt+2 (wrapped at tail into a dead buffer; keeps vmcnt uniform)
    {
      int pt = kt + 2; if (pt >= NK) pt -= NK;
      STAGE(pt, cur == 0 ? 2 : cur - 1);   // (cur+2)%3
    }

    __builtin_amdgcn_s_setprio(1);
    #pragma unroll
    for (int ks = 0; ks < 2; ++ks) {
      short8 ag[2], bg[2];
      #pragma unroll
      for (int i = 0; i < 2; ++i) {
        const int ar = wr + i * 16 + l15;
        ag[i] = *reinterpret_cast<const short8*>(reinterpret_cast<const char*>(As[cur]) +
                 ar * 128 + ((ks * 64 + l4 * 16) ^ ((ar & 7) << 4)));
        const int br = wc + i * 16 + l15;
        bg[i] = *reinterpret_cast<const short8*>(reinterpret_cast<const char*>(Bs[cur]) +
                 br * 128 + ((ks * 64 + l4 * 16) ^ ((br & 7) << 4)));
      }
      #pragma unroll
      for (int i = 0; i < 2; ++i)
        #pragma unroll
        for (int j = 0; j < 2; ++j)
          acc[i][j] = __builtin_amdgcn_mfma_f32_16x16x32_bf16(ag[i], bg[j], acc[i][j], 0, 0, 0);
    }
    __builtin_amdgcn_s_setprio(0);
    cur = (cur == 2) ? 0 : cur + 1;
  }

  // epilogue: C row = (lane>>4)*4 + reg, col = lane&15 (m89-verified layout)
  #pragma unroll
  for (int j = 0; j < 2; ++j) {
    const int gcol = n0 + wc + j * 16 + l15;
    const float bb = bias[gcol];
    #pragma unroll
    for (int i = 0; i < 2; ++i) {
      const int grow = m0 + wr + i * 16 + l4 * 4;
      if (mode == 2) {               // float32 output [M, DM]
        float* dst = reinterpret_cast<float*>(dstv);
        #pragma unroll
        for (int r = 0; r < 4; ++r)
          dst[(size_t)(grow + r) * DM + gcol] = acc[i][j][r] + bb;
      } else {
        u16* dst = reinterpret_cast<u16*>(dstv);
        const int b = grow >> 11, s = grow & (SEQ - 1);
        const int h = gcol >> 6, d = gcol & 63;
        if (mode == 0) {
          #pragma unroll
          for (int r = 0; r < 4; ++r)
            dst[((size_t)(b * H + h) * SEQ + s + r) * HD + d] = f2bf((acc[i][j][r] + bb) * outScale);
        } else {  // mode 1: V transposed — 4 consecutive s → one 8B store
          union { uint2 v; u16 e[4]; } pk;
          #pragma unroll
          for (int r = 0; r < 4; ++r) pk.e[r] = f2bf(acc[i][j][r] + bb);
          *reinterpret_cast<uint2*>(dst + ((size_t)(b * H + h) * HD + d) * SEQ + s) = pk.v;
        }
      }
    }
  }
}

__global__ __launch_bounds__(256) void gemm_qkv_kernel(
    const u16* __restrict__ Xb, const u16* __restrict__ wT,
    const float* __restrict__ bq, const float* __restrict__ bk, const float* __restrict__ bv,
    u16* __restrict__ Qb, u16* __restrict__ Kb, u16* __restrict__ Vtb)
{
  // 2304 blocks = 8 x 288: XCD-chunked bijective swizzle (T1)
  const int flat = blockIdx.z * 768 + blockIdx.y * 12 + blockIdx.x;
  const int nb = (flat & 7) * 288 + (flat >> 3);
  const int z = nb / 768, rem = nb % 768;
  const int by = rem / 12, bx = rem % 12;
  const u16* A      = Xb + (size_t)z * ((size_t)MROWS * DM);
  const u16* Bt     = wT + (size_t)z * DM * DM;
  const float* bias = z == 0 ? bq : z == 1 ? bk : bv;
  u16* dst          = z == 0 ? Qb : z == 1 ? Kb : Vtb;
  const float sc    = z == 1 ? C_SM : 1.0f;   // fold softmax scale*log2e into K
  gemm_bf16(A, Bt, bias, dst, z == 2 ? 1 : 0, bx, by, sc);
}

__global__ __launch_bounds__(256) void gemm_o_kernel(const u16* __restrict__ A, const u16* __restrict__ woT,
                                                     const float* __restrict__ bo, float* __restrict__ out)
{
  const int flat = blockIdx.y * 12 + blockIdx.x;       // 768 = 8 x 96
  const int nb = (flat & 7) * 96 + (flat >> 3);
  gemm_bf16(A, woT, bo, out, 2, nb % 12, nb / 12, 1.0f);
}

// ---------------- flash attention: QBLK=128 (4 waves x 32q), KV-SPLIT x2, 32x32x16 ----------
// R14 structure (best measured): triple-buffered K/V in LDS, prefetch 2 tiles ahead,
// steady-state s_waitcnt vmcnt(4) (never 0 in loop; wrapped prefetch keeps count uniform).
// Swapped QK^T, no max-tracking (K pre-scaled into exp2 domain; partials additive).
// P in registers via cvt_pk + v_permlane32_swap_b32 (HW-verified R10-R14).
// l via ones-MFMA on the P A-frag (accL). Merge is a separate dispatch (kernel
// boundary = the coherence mechanism; in-kernel agent-scope atomics flush per-XCD L2, R15).
__global__ __launch_bounds__(256) void attn_kernel(const u16* __restrict__ Q, const u16* __restrict__ K,
                                                   const u16* __restrict__ Vt,
                                                   float* __restrict__ Op0, float* __restrict__ Op1,
                                                   float* __restrict__ Lp0, float* __restrict__ Lp1)
{
  __shared__ u16 Ks[3][64 * 64];   // [kv][d] rows 128B, triple-buffered (24KB)
  __shared__ u16 Vs[3][64 * 64];   // [d][t]  rows 128B, triple-buffered (24KB)
  const int t = threadIdx.x;
  const int lane = t & 63, w = t >> 6;             // 4 waves
  const int l31 = lane & 31, hi = lane >> 5;
  const int flat = blockIdx.y * 32 + blockIdx.x;   // 768 = 8 x 96 (T1)
  const int nbid = (flat & 7) * 96 + (flat >> 3);
  const int bh = nbid >> 5;                        // 24
  const int rem = nbid & 31;
  const int q0 = (rem >> 1) * 128;                 // 16 q-tiles
  const int half = rem & 1;                        // kv half
  const int kv0 = half * (SEQ / 2);
  const size_t qbase  = ((size_t)bh * SEQ + q0) * HD;
  const size_t kbase0 = (size_t)bh * SEQ * HD;
  const size_t vtbase = (size_t)bh * HD * SEQ;
  float* __restrict__ Op = half ? Op1 : Op0;
  float* __restrict__ Lp = half ? Lp1 : Lp0;
  constexpr int NT = SEQ / 2 / 64;                 // 16 tiles

  // staging: chunk = 1024B = 8 rows x 128B; lane covers 16B at chunk + lane*16;
  // row-in-chunk = lane>>3; pre-swizzled global col = 8*((lane&7)^(row&7)).
  const int r8 = lane >> 3;
  const int pcol = ((lane & 7) ^ r8) * 8;

  // Q direct to registers: B-frag lane holds Q[q = w*32+l31][d = ks*16 + hi*8 + 0..7]
  short8 qf[4];
  {
    const u16* qp = Q + qbase + (size_t)(w * 32 + l31) * HD + hi * 8;
    #pragma unroll
    for (int ks = 0; ks < 4; ++ks)
      qf[ks] = *reinterpret_cast<const short8*>(qp + ks * 16);
  }

  // prefetch helper: stage kv-tile `pt` into buffer `buf` (4 gl2lds per wave)
  auto STAGE = [&](int pt, int buf) {
    #pragma unroll
    for (int j = 0; j < 2; ++j) {
      const int ci = w * 2 + j;
      const int row = ci * 8 + r8;
      gl2lds16(K + kbase0 + (size_t)(kv0 + pt * 64 + row) * HD + pcol, &Ks[buf][ci * 512]);
      gl2lds16(Vt + vtbase + (size_t)row * SEQ + kv0 + pt * 64 + pcol, &Vs[buf][ci * 512]);
    }
  };

  STAGE(0, 0);
  STAGE(1, 1);

  short8 ones;
  #pragma unroll
  for (int j = 0; j < 8; ++j) ones[j] = (short)0x3F80;   // bf16 1.0

  f32x16 oacc[2] = {};
  f32x16 accL = {};
  int cur = 0;   // buffer of tile kt; rotates 0,1,2

  for (int kt = 0; kt < NT; ++kt) {
    // T4: wait only for tile kt's 4 loads (tile kt+1's stay in flight across the barrier)
    asm volatile("s_waitcnt vmcnt(4)" ::: "memory");
    __builtin_amdgcn_s_barrier();

    // prefetch tile kt+2 (wrapped at the tail; keeps vmcnt count uniform, no conditionals)
    {
      const int pt = (kt + 2) & (NT - 1);
      const int pbuf = (cur + 2) % 3;
      STAGE(pt, pbuf);
    }

    // QK^T: s0/s1 = S^T tiles [kv 0-31 / 32-63][q = 32 own rows], exp2 domain.
    // C/D layout: col q = l31, row kv = (reg&3) + 8*(reg>>2) + 4*hi (+32 for s1)
    f32x16 s0 = {}, s1 = {};
    __builtin_amdgcn_s_setprio(1);
    #pragma unroll
    for (int ks = 0; ks < 4; ++ks) {
      const int cb = ks * 32 + hi * 16;
      short8 kf0 = *reinterpret_cast<const short8*>(reinterpret_cast<const char*>(Ks[cur]) +
                   l31 * 128 + (cb ^ ((l31 & 7) << 4)));
      short8 kf1 = *reinterpret_cast<const short8*>(reinterpret_cast<const char*>(Ks[cur]) +
                   (32 + l31) * 128 + (cb ^ ((l31 & 7) << 4)));
      s0 = __builtin_amdgcn_mfma_f32_32x32x16_bf16(kf0, qf[ks], s0, 0, 0, 0);
      s1 = __builtin_amdgcn_mfma_f32_32x32x16_bf16(kf1, qf[ks], s1, 0, 0, 0);
    }
    __builtin_amdgcn_s_setprio(0);

    // P = exp2(S')  — single v_exp_f32 each
    float p0[16], p1[16];
    #pragma unroll
    for (int r = 0; r < 16; ++r) {
      p0[r] = fexp2(s0[r]);
      p1[r] = fexp2(s1[r]);
    }

    // PV + row-sum: O[q][d] += P[q][kv] V[kv][d]; l[q] += sum P (ones-MFMA).
    // A-frag built in-register via cvt_pk + permlane32_swap (lane<->lane^32 == k-split).
    __builtin_amdgcn_s_setprio(1);
    #pragma unroll
    for (int ks2 = 0; ks2 < 4; ++ks2) {
      const float* P = (ks2 < 2) ? p0 : p1;    // compile-time after unroll
      const int ro = (ks2 & 1) * 8;
      u32 a0 = cvt_pk_bf16(P[ro + 0], P[ro + 1]);
      u32 a1 = cvt_pk_bf16(P[ro + 2], P[ro + 3]);
      u32 b0 = cvt_pk_bf16(P[ro + 4], P[ro + 5]);
      u32 b1 = cvt_pk_bf16(P[ro + 6], P[ro + 7]);
      asm volatile("v_permlane32_swap_b32 %0, %1" : "+v"(a0), "+v"(b0));
      asm volatile("v_permlane32_swap_b32 %0, %1" : "+v"(a1), "+v"(b1));
      union { u32 u[4]; short8 s; } pa;
      pa.u[0] = a0; pa.u[1] = a1; pa.u[2] = b0; pa.u[3] = b1;
      accL = __builtin_amdgcn_mfma_f32_32x32x16_bf16(pa.s, ones, accL, 0, 0, 0);
      #pragma unroll
      for (int dt = 0; dt < 2; ++dt) {
        const int vr = dt * 32 + l31;
        short8 vf = *reinterpret_cast<const short8*>(reinterpret_cast<const char*>(Vs[cur]) +
                    vr * 128 + ((ks2 * 32 + hi * 16) ^ ((vr & 7) << 4)));
        oacc[dt] = __builtin_amdgcn_mfma_f32_32x32x16_bf16(pa.s, vf, oacc[dt], 0, 0, 0);
      }
    }
    __builtin_amdgcn_s_setprio(0);
    cur = (cur == 2) ? 0 : cur + 1;
  }

  // write f32 partials: O rows [bh*SEQ + q][d]; l from accL (all cols equal)
  if (l31 == 0) {
    #pragma unroll
    for (int r = 0; r < 16; ++r) {
      const int qo = (r & 3) + 8 * (r >> 2) + 4 * hi;
      Lp[(size_t)bh * SEQ + q0 + w * 32 + qo] = accL[r];
    }
  }
  #pragma unroll
  for (int r = 0; r < 16; ++r) {
    const int qo = (r & 3) + 8 * (r >> 2) + 4 * hi;   // C/D row within wave's 32 q
    const size_t base = ((size_t)bh * SEQ + q0 + w * 32 + qo) * HD;
    Op[base + l31]      = oacc[0][r];
    Op[base + 32 + l31] = oacc[1][r];
  }
}

// ---------------- merge partials: Ab = bf16((O0+O1)/(l0+l1)), merged-head layout ------------
__global__ __launch_bounds__(256) void attn_merge(const float* __restrict__ Op0, const float* __restrict__ Op1,
                                                  const float* __restrict__ Lp0, const float* __restrict__ Lp1,
                                                  u16* __restrict__ Ab)
{
  const int id = blockIdx.x * 256 + threadIdx.x;   // one per 4 d-elems
  const int row = id >> 4, dc = (id & 15) * 4;     // row in [0, 24*2048)
  const int bh = row >> 11, q = row & (SEQ - 1);
  const int b = bh / H, h = bh % H;
  const float inv = 1.f / (Lp0[row] + Lp1[row]);
  float4 o0 = *reinterpret_cast<const float4*>(Op0 + (size_t)row * HD + dc);
  float4 o1 = *reinterpret_cast<const float4*>(Op1 + (size_t)row * HD + dc);
  uint2 o;
  o.x = cvt_pk_bf16((o0.x + o1.x) * inv, (o0.y + o1.y) * inv);
  o.y = cvt_pk_bf16((o0.z + o1.z) * inv, (o0.w + o1.w) * inv);
  *reinterpret_cast<uint2*>(Ab + ((size_t)(b * SEQ + q)) * DM + h * HD + dc) = o;
}

extern "C" void kernel_launch(void* const* d_in, const int* in_sizes, int n_in,
                              void* d_out, int out_size, void* d_ws, size_t ws_size,
                              hipStream_t stream)
{
  const float* q  = (const float*)d_in[0];
  const float* k  = (const float*)d_in[1];
  const float* v  = (const float*)d_in[2];
  const float* wq = (const float*)d_in[3];
  const float* bq = (const float*)d_in[4];
  const float* wk = (const float*)d_in[5];
  const float* bk = (const float*)d_in[6];
  const float* wv = (const float*)d_in[7];
  const float* bv = (const float*)d_in[8];
  const float* wo = (const float*)d_in[9];
  const float* bo = (const float*)d_in[10];

  u16* ws = (u16*)d_ws;
  const size_t WSZ = (size_t)DM * DM;            // 589,824
  const size_t TSZ = (size_t)MROWS * DM;         // 3,145,728 (= 24*2048*64)
  const size_t NQ  = (size_t)BATCH * H * SEQ;    // 49,152 q-rows
  u16* wT  = ws;                 // wqT, wkT, wvT, woT (4 x WSZ)
  u16* Qb  = ws + 4 * WSZ;       // [B,H,S,HD]
  u16* Kb  = Qb + TSZ;           // [B,H,S,HD], pre-scaled by C_SM
  u16* Vtb = Kb + TSZ;           // [B,H,HD,S]
  u16* Ab  = Vtb + TSZ;          // [M, DM] attention output (merged heads)
  float* Op0 = (float*)(Ab + TSZ);   // [NQ][HD] f32 partial O, kv half 0
  float* Op1 = Op0 + TSZ;            // half 1
  float* Lp0 = Op1 + TSZ;            // [NQ] f32 partial l
  float* Lp1 = Lp0 + NQ;
  u16* Xb  = (u16*)Op0;              // x in bf16 (3 x TSZ = 18.9MB) ALIASES Op0/Op1:
                                     // dead once qkv completes, before attn writes partials
  // total ws: (4*WSZ + 4*TSZ)*2B + (2*TSZ + 2*NQ)*4B ≈ 55.4 MB

  convert_x<<<dim3(2048), 256, 0, stream>>>(q, k, v, Xb);
  transpose_w4<<<dim3(12, 12, 4), 256, 0, stream>>>(wq, wk, wv, wo, wT);
  gemm_qkv_kernel<<<dim3(12, 64, 3), 256, 0, stream>>>(Xb, wT, bq, bk, bv, Qb, Kb, Vtb);
  attn_kernel<<<dim3(32, 24), 256, 0, stream>>>(Qb, Kb, Vtb, Op0, Op1, Lp0, Lp1);
  attn_merge<<<dim3((int)(NQ * 16 / 256)), 256, 0, stream>>>(Op0, Op1, Lp0, Lp1, Ab);
  gemm_o_kernel<<<dim3(12, 64), 256, 0, stream>>>(Ab, wT + 3 * WSZ, bo, (float*)d_out);
}

// Round 18
// 97.982 us; speedup vs baseline: 1.0583x; 1.0583x over previous
//
#include <hip/hip_runtime.h>

#define H 12
#define DM 768
#define HD 64
#define SEQ 2048
#define BATCH 2
#define MROWS (BATCH*SEQ)   // 4096

typedef __attribute__((ext_vector_type(8))) short short8;    // 8 bf16 (4 VGPRs)
typedef __attribute__((ext_vector_type(4))) float f32x4;
typedef __attribute__((ext_vector_type(16))) float f32x16;
using u16 = unsigned short;
using u32 = unsigned int;

__device__ __forceinline__ float bf2f(u16 u) { return __uint_as_float(((u32)u) << 16); }
__device__ __forceinline__ u16 f2bf(float x) {
  u32 u = __float_as_uint(x);
  return (u16)((u + 0x7fffu + ((u >> 16) & 1u)) >> 16);   // RNE
}
// packed f32x2 -> bf16x2 (RNE), single instruction (T12 recipe: no builtin on gfx950)
__device__ __forceinline__ u32 cvt_pk_bf16(float lo, float hi) {
  u32 r;
  asm("v_cvt_pk_bf16_f32 %0, %1, %2" : "=v"(r) : "v"(lo), "v"(hi));
  return r;
}
// guaranteed single-instruction exp2 (trans pipe)
__device__ __forceinline__ float fexp2(float x) {
  float r;
  asm("v_exp_f32 %0, %1" : "=v"(r) : "v"(x));
  return r;
}
// async global->LDS, 16B per lane; LDS dest = wave-uniform base + lane*16 (m97/m104)
__device__ __forceinline__ void gl2lds16(const u16* __restrict__ g, u16* l) {
  __builtin_amdgcn_global_load_lds(
      (const __attribute__((address_space(1))) unsigned int*)g,
      (__attribute__((address_space(3))) unsigned int*)l,
      16, 0, 0);
}

#define C_SM 0.18033688011112042f   // (1/sqrt(64)) * log2(e), folded into K

// ------------- weight transpose + f32->bf16: dst[e*768+d] = bf16(src[d*768+e]) -------------
__global__ __launch_bounds__(256) void transpose_w4(const float* __restrict__ w0, const float* __restrict__ w1,
                                                    const float* __restrict__ w2, const float* __restrict__ w3,
                                                    u16* __restrict__ dst0)
{
  __shared__ u16 Ts[64][72];                 // +8 pad, rows 144 B (16B-aligned)
  const float* src = blockIdx.z == 0 ? w0 : blockIdx.z == 1 ? w1 : blockIdx.z == 2 ? w2 : w3;
  u16* dst = dst0 + (size_t)blockIdx.z * DM * DM;
  const int t = threadIdx.x;
  const int r0 = blockIdx.y * 64, c0 = blockIdx.x * 64;
  const int row = t >> 2, cq = (t & 3) * 16;
  const float* sp = src + (size_t)(r0 + row) * DM + c0 + cq;
  #pragma unroll
  for (int g = 0; g < 4; ++g) {
    float4 a = *reinterpret_cast<const float4*>(sp + g * 4);
    Ts[row][cq + g * 4 + 0] = f2bf(a.x);
    Ts[row][cq + g * 4 + 1] = f2bf(a.y);
    Ts[row][cq + g * 4 + 2] = f2bf(a.z);
    Ts[row][cq + g * 4 + 3] = f2bf(a.w);
  }
  __syncthreads();
  union { uint4 v[2]; u16 e[16]; } pk;
  #pragma unroll
  for (int j = 0; j < 16; ++j) pk.e[j] = Ts[cq + j][row];
  uint4* dp = reinterpret_cast<uint4*>(dst + (size_t)(c0 + row) * DM + r0 + cq);
  dp[0] = pk.v[0];
  dp[1] = pk.v[1];
}

// ---------------- GEMM (f32 A): C[m][n] = (A . Bt + bias) * outScale — R16-proven ----------
// BM x 128 tile, BK=64, 4 waves, wave-tile (BM/2) x 64. Inline staging,
// XOR swizzle byte ^= (row&7)<<4 on write and read (T2, G4).
template<int BM, bool AF32>
__device__ __forceinline__ void gemm_core(const void* __restrict__ Av, const u16* __restrict__ Bt,
                                          const float* __restrict__ bias, void* __restrict__ dstv,
                                          int mode, int bx, int by, float outScale)
{
  constexpr int AFR = BM / 32;
  constexpr int ACH = BM / 32;
  __shared__ u16 As[BM * 64];
  __shared__ u16 Bs[128 * 64];
  const int t = threadIdx.x;
  const int lane = t & 63, w = t >> 6;
  const int l15 = lane & 15, l4 = lane >> 4;
  const int m0 = by * BM, n0 = bx * 128;
  const int wr = (w >> 1) * (BM / 2), wc = (w & 1) * 64;

  f32x4 acc[AFR][4] = {};

  for (int kt = 0; kt < DM / 64; ++kt) {
    const int k0 = kt * 64;
    #pragma unroll
    for (int c = 0; c < ACH; ++c) {           // A tile: BM x 64
      const int id = c * 256 + t;
      const int row = id >> 3, xc = id & 7;
      const int db = row * 128 + ((xc * 16) ^ ((row & 7) << 4));
      if (AF32) {
        const float* Af = reinterpret_cast<const float*>(Av) + (size_t)(m0 + row) * DM + k0 + xc * 8;
        float4 a0 = *reinterpret_cast<const float4*>(Af);
        float4 a1 = *reinterpret_cast<const float4*>(Af + 4);
        uint4 v;
        v.x = cvt_pk_bf16(a0.x, a0.y);
        v.y = cvt_pk_bf16(a0.z, a0.w);
        v.z = cvt_pk_bf16(a1.x, a1.y);
        v.w = cvt_pk_bf16(a1.z, a1.w);
        *reinterpret_cast<uint4*>(reinterpret_cast<char*>(As) + db) = v;
      } else {
        uint4 va = *reinterpret_cast<const uint4*>(reinterpret_cast<const u16*>(Av) +
                   (size_t)(m0 + row) * DM + k0 + xc * 8);
        *reinterpret_cast<uint4*>(reinterpret_cast<char*>(As) + db) = va;
      }
    }
    #pragma unroll
    for (int c = 0; c < 4; ++c) {             // B tile: 128 x 64
      const int id = c * 256 + t;
      const int row = id >> 3, xc = id & 7;
      const int db = row * 128 + ((xc * 16) ^ ((row & 7) << 4));
      uint4 vb = *reinterpret_cast<const uint4*>(Bt + (size_t)(n0 + row) * DM + k0 + xc * 8);
      *reinterpret_cast<uint4*>(reinterpret_cast<char*>(Bs) + db) = vb;
    }
    __syncthreads();
    #pragma unroll
    for (int ks = 0; ks < 2; ++ks) {
      short8 ag[AFR], bg[4];
      #pragma unroll
      for (int i = 0; i < AFR; ++i) {
        const int ar = wr + i * 16 + l15;
        ag[i] = *reinterpret_cast<const short8*>(reinterpret_cast<const char*>(As) +
                 ar * 128 + ((ks * 64 + l4 * 16) ^ ((ar & 7) << 4)));
      }
      #pragma unroll
      for (int j = 0; j < 4; ++j) {
        const int br = wc + j * 16 + l15;
        bg[j] = *reinterpret_cast<const short8*>(reinterpret_cast<const char*>(Bs) +
                 br * 128 + ((ks * 64 + l4 * 16) ^ ((br & 7) << 4)));
      }
      #pragma unroll
      for (int i = 0; i < AFR; ++i)
        #pragma unroll
        for (int j = 0; j < 4; ++j)
          acc[i][j] = __builtin_amdgcn_mfma_f32_16x16x32_bf16(ag[i], bg[j], acc[i][j], 0, 0, 0);
    }
    __syncthreads();
  }

  // epilogue: C row = (lane>>4)*4 + reg, col = lane&15 (m89-verified layout)
  #pragma unroll
  for (int j = 0; j < 4; ++j) {
    const int gcol = n0 + wc + j * 16 + l15;
    const float bb = bias[gcol];
    #pragma unroll
    for (int i = 0; i < AFR; ++i) {
      const int grow = m0 + wr + i * 16 + l4 * 4;
      if (mode == 2) {
        float* dst = reinterpret_cast<float*>(dstv);
        #pragma unroll
        for (int r = 0; r < 4; ++r)
          dst[(size_t)(grow + r) * DM + gcol] = acc[i][j][r] + bb;
      } else {
        u16* dst = reinterpret_cast<u16*>(dstv);
        const int b = grow >> 11, s = grow & (SEQ - 1);
        const int h = gcol >> 6, d = gcol & 63;
        if (mode == 0) {
          #pragma unroll
          for (int r = 0; r < 4; ++r)
            dst[((size_t)(b * H + h) * SEQ + s + r) * HD + d] = f2bf((acc[i][j][r] + bb) * outScale);
        } else {  // mode 1: V transposed — 4 consecutive s → one 8B store
          union { uint2 v; u16 e[4]; } pk;
          #pragma unroll
          for (int r = 0; r < 4; ++r) pk.e[r] = f2bf(acc[i][j][r] + bb);
          *reinterpret_cast<uint2*>(dst + ((size_t)(b * H + h) * HD + d) * SEQ + s) = pk.v;
        }
      }
    }
  }
}

// ---------------- GEMM (bf16 A, T4 pipeline) — for o-projection only ----------------
// 64x64 tile, BK=64, 4 waves (2x2). Triple-buffered global_load_lds staging
// (pre-swizzled source), prefetch 2 ahead, steady-state vmcnt(4), 1 barrier/iter.
__device__ __forceinline__ void gemm_bf16(const u16* __restrict__ A, const u16* __restrict__ Bt,
                                          const float* __restrict__ bias, float* __restrict__ dst,
                                          int bx, int by)
{
  __shared__ u16 As[3][64 * 64];
  __shared__ u16 Bs[3][64 * 64];
  const int t = threadIdx.x;
  const int lane = t & 63, w = t >> 6;
  const int l15 = lane & 15, l4 = lane >> 4;
  const int m0 = by * 64, n0 = bx * 64;
  const int wr = (w >> 1) * 32, wc = (w & 1) * 32;
  constexpr int NK = DM / 64;      // 12
  const int r8 = lane >> 3;
  const int pcol = ((lane & 7) ^ r8) * 8;

  auto STAGE = [&](int kt2, int buf) {
    const int k0 = kt2 * 64;
    #pragma unroll
    for (int j = 0; j < 2; ++j) {
      const int ci = w * 2 + j;
      const int row = ci * 8 + r8;
      gl2lds16(A  + (size_t)(m0 + row) * DM + k0 + pcol, &As[buf][ci * 512]);
      gl2lds16(Bt + (size_t)(n0 + row) * DM + k0 + pcol, &Bs[buf][ci * 512]);
    }
  };

  STAGE(0, 0);
  STAGE(1, 1);

  f32x4 acc[2][2] = {};
  int cur = 0;

  for (int kt = 0; kt < NK; ++kt) {
    asm volatile("s_waitcnt vmcnt(4)" ::: "memory");
    __builtin_amdgcn_s_barrier();
    {
      int pt = kt + 2; if (pt >= NK) pt -= NK;
      STAGE(pt, cur == 0 ? 2 : cur - 1);   // (cur+2)%3
    }
    __builtin_amdgcn_s_setprio(1);
    #pragma unroll
    for (int ks = 0; ks < 2; ++ks) {
      short8 ag[2], bg[2];
      #pragma unroll
      for (int i = 0; i < 2; ++i) {
        const int ar = wr + i * 16 + l15;
        ag[i] = *reinterpret_cast<const short8*>(reinterpret_cast<const char*>(As[cur]) +
                 ar * 128 + ((ks * 64 + l4 * 16) ^ ((ar & 7) << 4)));
        const int br = wc + i * 16 + l15;
        bg[i] = *reinterpret_cast<const short8*>(reinterpret_cast<const char*>(Bs[cur]) +
                 br * 128 + ((ks * 64 + l4 * 16) ^ ((br & 7) << 4)));
      }
      #pragma unroll
      for (int i = 0; i < 2; ++i)
        #pragma unroll
        for (int j = 0; j < 2; ++j)
          acc[i][j] = __builtin_amdgcn_mfma_f32_16x16x32_bf16(ag[i], bg[j], acc[i][j], 0, 0, 0);
    }
    __builtin_amdgcn_s_setprio(0);
    cur = (cur == 2) ? 0 : cur + 1;
  }

  #pragma unroll
  for (int j = 0; j < 2; ++j) {
    const int gcol = n0 + wc + j * 16 + l15;
    const float bb = bias[gcol];
    #pragma unroll
    for (int i = 0; i < 2; ++i) {
      const int grow = m0 + wr + i * 16 + l4 * 4;
      #pragma unroll
      for (int r = 0; r < 4; ++r)
        dst[(size_t)(grow + r) * DM + gcol] = acc[i][j][r] + bb;
    }
  }
}

__global__ __launch_bounds__(256) void gemm_qkv_kernel(
    const float* __restrict__ xq, const float* __restrict__ xk, const float* __restrict__ xv,
    const u16* __restrict__ wT, const float* __restrict__ bq, const float* __restrict__ bk,
    const float* __restrict__ bv, u16* __restrict__ Qb, u16* __restrict__ Kb, u16* __restrict__ Vtb)
{
  // 1152 blocks = 8 x 144: XCD-chunked bijective swizzle (T1)
  const int flat = blockIdx.z * 384 + blockIdx.y * 6 + blockIdx.x;
  const int nb = (flat & 7) * 144 + (flat >> 3);
  const int z = nb / 384, rem = nb % 384;
  const int by = rem / 6, bx = rem % 6;
  const float* A    = z == 0 ? xq : z == 1 ? xk : xv;
  const u16* Bt     = wT + (size_t)z * DM * DM;
  const float* bias = z == 0 ? bq : z == 1 ? bk : bv;
  u16* dst          = z == 0 ? Qb : z == 1 ? Kb : Vtb;
  const float sc    = z == 1 ? C_SM : 1.0f;   // fold softmax scale*log2e into K
  gemm_core<64, true>(A, Bt, bias, dst, z == 2 ? 1 : 0, bx, by, sc);
}

__global__ __launch_bounds__(256) void gemm_o_kernel(const u16* __restrict__ A, const u16* __restrict__ woT,
                                                     const float* __restrict__ bo, float* __restrict__ out)
{
  const int flat = blockIdx.y * 12 + blockIdx.x;       // 768 = 8 x 96
  const int nb = (flat & 7) * 96 + (flat >> 3);
  gemm_bf16(A, woT, bo, out, nb % 12, nb / 12);
}

// ---------------- flash attention: QBLK=128 (4 waves x 32q), KV-SPLIT x2, 32x32x16 ----------
// R14/R16 structure (best measured): triple-buffered K/V in LDS, prefetch 2 tiles ahead,
// steady-state s_waitcnt vmcnt(4) (never 0 in loop). Swapped QK^T, no max-tracking
// (K pre-scaled into exp2 domain; partials additive). P in registers via cvt_pk +
// v_permlane32_swap_b32. l via ones-MFMA (accL). Merge = separate dispatch (G16).
__global__ __launch_bounds__(256) void attn_kernel(const u16* __restrict__ Q, const u16* __restrict__ K,
                                                   const u16* __restrict__ Vt,
                                                   float* __restrict__ Op0, float* __restrict__ Op1,
                                                   float* __restrict__ Lp0, float* __restrict__ Lp1)
{
  __shared__ u16 Ks[3][64 * 64];
  __shared__ u16 Vs[3][64 * 64];
  const int t = threadIdx.x;
  const int lane = t & 63, w = t >> 6;
  const int l31 = lane & 31, hi = lane >> 5;
  const int flat = blockIdx.y * 32 + blockIdx.x;   // 768 = 8 x 96 (T1)
  const int nbid = (flat & 7) * 96 + (flat >> 3);
  const int bh = nbid >> 5;
  const int rem = nbid & 31;
  const int q0 = (rem >> 1) * 128;
  const int half = rem & 1;
  const int kv0 = half * (SEQ / 2);
  const size_t qbase  = ((size_t)bh * SEQ + q0) * HD;
  const size_t kbase0 = (size_t)bh * SEQ * HD;
  const size_t vtbase = (size_t)bh * HD * SEQ;
  float* __restrict__ Op = half ? Op1 : Op0;
  float* __restrict__ Lp = half ? Lp1 : Lp0;
  constexpr int NT = SEQ / 2 / 64;                 // 16 tiles

  const int r8 = lane >> 3;
  const int pcol = ((lane & 7) ^ r8) * 8;

  short8 qf[4];
  {
    const u16* qp = Q + qbase + (size_t)(w * 32 + l31) * HD + hi * 8;
    #pragma unroll
    for (int ks = 0; ks < 4; ++ks)
      qf[ks] = *reinterpret_cast<const short8*>(qp + ks * 16);
  }

  auto STAGE = [&](int pt, int buf) {
    #pragma unroll
    for (int j = 0; j < 2; ++j) {
      const int ci = w * 2 + j;
      const int row = ci * 8 + r8;
      gl2lds16(K + kbase0 + (size_t)(kv0 + pt * 64 + row) * HD + pcol, &Ks[buf][ci * 512]);
      gl2lds16(Vt + vtbase + (size_t)row * SEQ + kv0 + pt * 64 + pcol, &Vs[buf][ci * 512]);
    }
  };

  STAGE(0, 0);
  STAGE(1, 1);

  short8 ones;
  #pragma unroll
  for (int j = 0; j < 8; ++j) ones[j] = (short)0x3F80;   // bf16 1.0

  f32x16 oacc[2] = {};
  f32x16 accL = {};
  int cur = 0;

  for (int kt = 0; kt < NT; ++kt) {
    asm volatile("s_waitcnt vmcnt(4)" ::: "memory");
    __builtin_amdgcn_s_barrier();
    {
      const int pt = (kt + 2) & (NT - 1);
      const int pbuf = (cur + 2) % 3;
      STAGE(pt, pbuf);
    }

    f32x16 s0 = {}, s1 = {};
    __builtin_amdgcn_s_setprio(1);
    #pragma unroll
    for (int ks = 0; ks < 4; ++ks) {
      const int cb = ks * 32 + hi * 16;
      short8 kf0 = *reinterpret_cast<const short8*>(reinterpret_cast<const char*>(Ks[cur]) +
                   l31 * 128 + (cb ^ ((l31 & 7) << 4)));
      short8 kf1 = *reinterpret_cast<const short8*>(reinterpret_cast<const char*>(Ks[cur]) +
                   (32 + l31) * 128 + (cb ^ ((l31 & 7) << 4)));
      s0 = __builtin_amdgcn_mfma_f32_32x32x16_bf16(kf0, qf[ks], s0, 0, 0, 0);
      s1 = __builtin_amdgcn_mfma_f32_32x32x16_bf16(kf1, qf[ks], s1, 0, 0, 0);
    }
    __builtin_amdgcn_s_setprio(0);

    float p0[16], p1[16];
    #pragma unroll
    for (int r = 0; r < 16; ++r) {
      p0[r] = fexp2(s0[r]);
      p1[r] = fexp2(s1[r]);
    }

    __builtin_amdgcn_s_setprio(1);
    #pragma unroll
    for (int ks2 = 0; ks2 < 4; ++ks2) {
      const float* P = (ks2 < 2) ? p0 : p1;
      const int ro = (ks2 & 1) * 8;
      u32 a0 = cvt_pk_bf16(P[ro + 0], P[ro + 1]);
      u32 a1 = cvt_pk_bf16(P[ro + 2], P[ro + 3]);
      u32 b0 = cvt_pk_bf16(P[ro + 4], P[ro + 5]);
      u32 b1 = cvt_pk_bf16(P[ro + 6], P[ro + 7]);
      asm volatile("v_permlane32_swap_b32 %0, %1" : "+v"(a0), "+v"(b0));
      asm volatile("v_permlane32_swap_b32 %0, %1" : "+v"(a1), "+v"(b1));
      union { u32 u[4]; short8 s; } pa;
      pa.u[0] = a0; pa.u[1] = a1; pa.u[2] = b0; pa.u[3] = b1;
      accL = __builtin_amdgcn_mfma_f32_32x32x16_bf16(pa.s, ones, accL, 0, 0, 0);
      #pragma unroll
      for (int dt = 0; dt < 2; ++dt) {
        const int vr = dt * 32 + l31;
        short8 vf = *reinterpret_cast<const short8*>(reinterpret_cast<const char*>(Vs[cur]) +
                    vr * 128 + ((ks2 * 32 + hi * 16) ^ ((vr & 7) << 4)));
        oacc[dt] = __builtin_amdgcn_mfma_f32_32x32x16_bf16(pa.s, vf, oacc[dt], 0, 0, 0);
      }
    }
    __builtin_amdgcn_s_setprio(0);
    cur = (cur == 2) ? 0 : cur + 1;
  }

  if (l31 == 0) {
    #pragma unroll
    for (int r = 0; r < 16; ++r) {
      const int qo = (r & 3) + 8 * (r >> 2) + 4 * hi;
      Lp[(size_t)bh * SEQ + q0 + w * 32 + qo] = accL[r];
    }
  }
  #pragma unroll
  for (int r = 0; r < 16; ++r) {
    const int qo = (r & 3) + 8 * (r >> 2) + 4 * hi;
    const size_t base = ((size_t)bh * SEQ + q0 + w * 32 + qo) * HD;
    Op[base + l31]      = oacc[0][r];
    Op[base + 32 + l31] = oacc[1][r];
  }
}

// ---------------- merge partials: Ab = bf16((O0+O1)/(l0+l1)), 8 elems/lane ------------------
__global__ __launch_bounds__(256) void attn_merge(const float* __restrict__ Op0, const float* __restrict__ Op1,
                                                  const float* __restrict__ Lp0, const float* __restrict__ Lp1,
                                                  u16* __restrict__ Ab)
{
  const int id = blockIdx.x * 256 + threadIdx.x;   // one per 8 d-elems
  const int row = id >> 3, dc = (id & 7) * 8;      // row in [0, 24*2048)
  const int bh = row >> 11, q = row & (SEQ - 1);
  const int b = bh / H, h = bh % H;
  const float inv = 1.f / (Lp0[row] + Lp1[row]);
  const float* p0 = Op0 + (size_t)row * HD + dc;
  const float* p1 = Op1 + (size_t)row * HD + dc;
  float4 a0 = *reinterpret_cast<const float4*>(p0);
  float4 a1 = *reinterpret_cast<const float4*>(p0 + 4);
  float4 c0 = *reinterpret_cast<const float4*>(p1);
  float4 c1 = *reinterpret_cast<const float4*>(p1 + 4);
  uint4 o;
  o.x = cvt_pk_bf16((a0.x + c0.x) * inv, (a0.y + c0.y) * inv);
  o.y = cvt_pk_bf16((a0.z + c0.z) * inv, (a0.w + c0.w) * inv);
  o.z = cvt_pk_bf16((a1.x + c1.x) * inv, (a1.y + c1.y) * inv);
  o.w = cvt_pk_bf16((a1.z + c1.z) * inv, (a1.w + c1.w) * inv);
  *reinterpret_cast<uint4*>(Ab + ((size_t)(b * SEQ + q)) * DM + h * HD + dc) = o;
}

extern "C" void kernel_launch(void* const* d_in, const int* in_sizes, int n_in,
                              void* d_out, int out_size, void* d_ws, size_t ws_size,
                              hipStream_t stream)
{
  const float* q  = (const float*)d_in[0];
  const float* k  = (const float*)d_in[1];
  const float* v  = (const float*)d_in[2];
  const float* wq = (const float*)d_in[3];
  const float* bq = (const float*)d_in[4];
  const float* wk = (const float*)d_in[5];
  const float* bk = (const float*)d_in[6];
  const float* wv = (const float*)d_in[7];
  const float* bv = (const float*)d_in[8];
  const float* wo = (const float*)d_in[9];
  const float* bo = (const float*)d_in[10];

  u16* ws = (u16*)d_ws;
  const size_t WSZ = (size_t)DM * DM;            // 589,824
  const size_t TSZ = (size_t)MROWS * DM;         // 3,145,728 (= 24*2048*64)
  const size_t NQ  = (size_t)BATCH * H * SEQ;    // 49,152 q-rows
  u16* wT  = ws;                 // wqT, wkT, wvT, woT (4 x WSZ)
  u16* Qb  = ws + 4 * WSZ;       // [B,H,S,HD]
  u16* Kb  = Qb + TSZ;           // [B,H,S,HD], pre-scaled by C_SM
  u16* Vtb = Kb + TSZ;           // [B,H,HD,S]
  u16* Ab  = Vtb + TSZ;          // [M, DM] attention output (merged heads)
  float* Op0 = (float*)(Ab + TSZ);   // [NQ][HD] f32 partial O, kv half 0
  float* Op1 = Op0 + TSZ;            // half 1
  float* Lp0 = Op1 + TSZ;            // [NQ] f32 partial l
  float* Lp1 = Lp0 + NQ;
  // total ws: (4*WSZ + 4*TSZ)*2B + (2*TSZ + 2*NQ)*4B ≈ 55.4 MB

  transpose_w4<<<dim3(12, 12, 4), 256, 0, stream>>>(wq, wk, wv, wo, wT);
  gemm_qkv_kernel<<<dim3(6, 64, 3), 256, 0, stream>>>(q, k, v, wT, bq, bk, bv, Qb, Kb, Vtb);
  attn_kernel<<<dim3(32, 24), 256, 0, stream>>>(Qb, Kb, Vtb, Op0, Op1, Lp0, Lp1);
  attn_merge<<<dim3((int)(NQ * 8 / 256)), 256, 0, stream>>>(Op0, Op1, Lp0, Lp1, Ab);
  gemm_o_kernel<<<dim3(12, 64), 256, 0, stream>>>(Ab, wT + 3 * WSZ, bo, (float*)d_out);
}